// Round 1
// 136.863 us; speedup vs baseline: 1.0740x; 1.0740x over previous
//
#include <hip/hip_runtime.h>

#define DD 128
#define CAP 12288          // per-bucket slot capacity (mean 8163, +45 sigma)

typedef __attribute__((ext_vector_type(8))) short bf16x8;
typedef __attribute__((ext_vector_type(4))) float f32x4;

__device__ inline unsigned short f2b(float f) {
    unsigned int u = __float_as_uint(f);
    u += 0x7fffu + ((u >> 16) & 1u);   // RNE
    return (unsigned short)(u >> 16);
}

// accumulate 4 bf16 (packed in uint2) into float4
__device__ inline void bacc(float4& a, uint2 v) {
    a.x += __uint_as_float(v.x << 16);
    a.y += __uint_as_float(v.x & 0xffff0000u);
    a.z += __uint_as_float(v.y << 16);
    a.w += __uint_as_float(v.y & 0xffff0000u);
}

// accumulate 8 bf16 (packed in uint4) into two float4
__device__ inline void bacc16(float4& a, float4& b, uint4 v) {
    a.x += __uint_as_float(v.x << 16);
    a.y += __uint_as_float(v.x & 0xffff0000u);
    a.z += __uint_as_float(v.y << 16);
    a.w += __uint_as_float(v.y & 0xffff0000u);
    b.x += __uint_as_float(v.z << 16);
    b.y += __uint_as_float(v.z & 0xffff0000u);
    b.z += __uint_as_float(v.w << 16);
    b.w += __uint_as_float(v.w & 0xffff0000u);
}

// ---- init per-bucket global cursors to region bases ----
__global__ void k_init(int* __restrict__ cur, int nbuck) {
    int b = blockIdx.x * 256 + threadIdx.x;
    if (b < nbuck) cur[b] = b * CAP;
}

// ---- phase A: bin edges by coarse bucket (dst>>9), pack (src<<9)|(dst&511) ----
__global__ __launch_bounds__(256) void k_binA(const int* __restrict__ src,
                                              const int* __restrict__ dst, int E,
                                              int chunk, int nbuck,
                                              int* __restrict__ cur,
                                              int* __restrict__ binned) {
    __shared__ int hist[256];
    __shared__ int base[256];
    __shared__ int curs[256];
    const int t = threadIdx.x;
    const int e0 = blockIdx.x * chunk;
    const int e1 = min(e0 + chunk, E);

    if (t < 256) { hist[t] = 0; curs[t] = 0; }
    __syncthreads();
    for (int e = e0 + t; e < e1; e += 256)
        atomicAdd(&hist[dst[e] >> 9], 1);
    __syncthreads();
    if (t < nbuck && hist[t] > 0)
        base[t] = atomicAdd(&cur[t], hist[t]);
    __syncthreads();
    for (int e = e0 + t; e < e1; e += 256) {
        int d = dst[e];
        int b = d >> 9;
        int p = atomicAdd(&curs[b], 1);
        int idx = base[b] + p;
        if (idx < (b + 1) * CAP)                     // statistical overflow guard
            binned[idx] = (src[e] << 9) | (d & 511);
    }
}

// ---- phase B: per-bucket LDS counting sort; emits CSR off/cnt/dinv + sorted src ----
__global__ __launch_bounds__(512) void k_binB(int* __restrict__ binned,
                                              const int* __restrict__ cur,
                                              int* __restrict__ off,
                                              int* __restrict__ cnt,
                                              float* __restrict__ dinv,
                                              int n) {
    __shared__ int hist[512];
    __shared__ int curs[512];
    __shared__ int sorted[CAP];
    const int t = threadIdx.x;
    const int b = blockIdx.x;
    const int base = b * CAP;
    const int cb = cur[b] - base;        // edges in this bucket

    hist[t] = 0;
    __syncthreads();
    for (int i = t; i < cb; i += 512)
        atomicAdd(&hist[binned[base + i] & 511], 1);
    __syncthreads();
    int v = hist[t];
    for (int st = 1; st < 512; st <<= 1) {
        int tv = (t >= st) ? hist[t - st] : 0;
        __syncthreads();
        hist[t] += tv;
        __syncthreads();
    }
    int excl = hist[t] - v;
    curs[t] = excl;
    int d = b * 512 + t;
    if (d < n) {
        off[d]  = base + excl;
        cnt[d]  = v;
        dinv[d] = rsqrtf((float)v + 1.0f);
    }
    __syncthreads();
    for (int i = t; i < cb; i += 512) {
        int pk = binned[base + i];
        int p = atomicAdd(&curs[pk & 511], 1);
        sorted[p] = pk >> 9;
    }
    __syncthreads();
    for (int i = t; i < cb; i += 512)
        binned[base + i] = sorted[i];
}

// ---- W [k][c] fp32 -> Wt [c][k] bf16 (32 KB, L2-resident) ----
__global__ __launch_bounds__(256) void k_wt(const float* __restrict__ W,
                                            unsigned short* __restrict__ Wt) {
    int idx = blockIdx.x * 256 + threadIdx.x;
    int k = idx >> 7, c = idx & 127;
    Wt[c * DD + k] = f2b(W[k * DD + c]);
}

// ---- hs[r][c] = bf16( (x[r,:] @ W[:,c]) * dinv[r] ), MFMA bf16 ----
__global__ __launch_bounds__(256) void k_gemm(const float* __restrict__ x,
                                              const unsigned short* __restrict__ Wt,
                                              const float* __restrict__ dinv,
                                              unsigned short* __restrict__ hs,
                                              int n) {
    const int t = threadIdx.x;
    const int wave = t >> 6, lane = t & 63;
    const int rowbase = blockIdx.x * 256 + wave * 64;
    const int l15 = lane & 15, l4 = lane >> 4;

    bf16x8 a[4][4];
    #pragma unroll
    for (int rb = 0; rb < 4; ++rb) {
        int r = rowbase + rb * 16 + l15;
        int rc = min(r, n - 1);
        const float* xr = x + (size_t)rc * DD;
        #pragma unroll
        for (int kc = 0; kc < 4; ++kc) {
            int k0 = kc * 32 + l4 * 8;
            float4 f0 = *(const float4*)(xr + k0);
            float4 f1 = *(const float4*)(xr + k0 + 4);
            bf16x8 fr;
            fr[0] = (short)f2b(f0.x); fr[1] = (short)f2b(f0.y);
            fr[2] = (short)f2b(f0.z); fr[3] = (short)f2b(f0.w);
            fr[4] = (short)f2b(f1.x); fr[5] = (short)f2b(f1.y);
            fr[6] = (short)f2b(f1.z); fr[7] = (short)f2b(f1.w);
            a[rb][kc] = fr;
        }
    }

    float dv[4][4];
    #pragma unroll
    for (int rb = 0; rb < 4; ++rb)
        #pragma unroll
        for (int vv = 0; vv < 4; ++vv) {
            int r = rowbase + rb * 16 + l4 * 4 + vv;
            dv[rb][vv] = dinv[min(r, n - 1)];
        }

    #pragma unroll
    for (int cb = 0; cb < 8; ++cb) {
        int c0 = cb * 16;
        f32x4 acc[4] = {};
        #pragma unroll
        for (int kc = 0; kc < 4; ++kc) {
            bf16x8 bfrag = *(const bf16x8*)(Wt + (size_t)(c0 + l15) * DD + kc * 32 + l4 * 8);
            #pragma unroll
            for (int rb = 0; rb < 4; ++rb)
                acc[rb] = __builtin_amdgcn_mfma_f32_16x16x32_bf16(a[rb][kc], bfrag, acc[rb], 0, 0, 0);
        }
        #pragma unroll
        for (int rb = 0; rb < 4; ++rb) {
            int r0 = rowbase + rb * 16 + l4 * 4;
            #pragma unroll
            for (int vv = 0; vv < 4; ++vv) {
                int r = r0 + vv;
                if (r < n)
                    hs[(size_t)r * DD + c0 + l15] = f2b(acc[rb][vv] * dv[rb][vv]);
            }
        }
    }
}

// ---- out[d] = (hs[d] + sum_{s in N(d)} hs[s]) * dinv[d] + b
// one wave/node; 4 quarter-waves each gather a DIFFERENT neighbor row
// (uint4 = 16B/lane x 16 lanes = 256B row). All idx loads for the node are
// issued first, then up to 6 row-gathers (24 edges) are in flight at once:
// ONE latency exposure per node instead of one per 8 edges.
__global__ __launch_bounds__(256, 8) void k_agg(const uint4* __restrict__ hsr,  // hs, row = 16 uint4
                                                const int* __restrict__ ssrc,
                                                const int* __restrict__ off,
                                                const int* __restrict__ cnt,
                                                const float* __restrict__ dinv,
                                                const float* __restrict__ bias,
                                                float* __restrict__ out, int n) {
    const int t = threadIdx.x;
    const int wave = t >> 6, lane = t & 63;
    const int q  = lane >> 4;      // quarter id 0..3
    const int ql = lane & 15;      // lane within quarter; covers bf16 cols [ql*8, ql*8+8)
    const int d = blockIdx.x * 4 + wave;
    if (d >= n) return;

    const int s0 = off[d];
    const int c  = cnt[d];

    float4 accA = {0.f, 0.f, 0.f, 0.f};
    float4 accB = {0.f, 0.f, 0.f, 0.f};

    // self row (independent, issues immediately)
    uint4 vself = hsr[(size_t)d * 16 + ql];

    // batch idx loads: 6 independent broadcast loads (quarter q, round r -> edge r*4+q)
    int idx[6];
    #pragma unroll
    for (int r = 0; r < 6; ++r) {
        int e = r * 4 + q;
        idx[r] = ssrc[s0 + ((e < c) ? e : 0)];   // in-bounds addr even when inactive
    }
    #pragma unroll
    for (int r = 0; r < 6; ++r) {
        int e = r * 4 + q;
        idx[r] = (e < c) ? idx[r] : d;           // inactive slots gather own row (safe)
    }

    // batch gathers: 6 independent 256B row reads in flight simultaneously
    uint4 val[6];
    #pragma unroll
    for (int r = 0; r < 6; ++r)
        val[r] = hsr[(size_t)idx[r] * 16 + ql];

    if (q == 0) bacc16(accA, accB, vself);
    #pragma unroll
    for (int r = 0; r < 6; ++r) {
        int e = r * 4 + q;
        if (e < c) bacc16(accA, accB, val[r]);
    }

    // rare tail: c > 24 (P ~ 2% at mean degree 16)
    for (int i = 24 + q; i < c; i += 4) {
        int s = ssrc[s0 + i];
        uint4 v = hsr[(size_t)s * 16 + ql];
        bacc16(accA, accB, v);
    }

    // fold the 4 quarters (bits 4 and 5 of lane id)
    #pragma unroll
    for (int m = 16; m <= 32; m <<= 1) {
        accA.x += __shfl_xor(accA.x, m);
        accA.y += __shfl_xor(accA.y, m);
        accA.z += __shfl_xor(accA.z, m);
        accA.w += __shfl_xor(accA.w, m);
        accB.x += __shfl_xor(accB.x, m);
        accB.y += __shfl_xor(accB.y, m);
        accB.z += __shfl_xor(accB.z, m);
        accB.w += __shfl_xor(accB.w, m);
    }

    if (q == 0) {
        float di = dinv[d];
        float4 b0 = ((const float4*)bias)[ql * 2];
        float4 b1 = ((const float4*)bias)[ql * 2 + 1];
        float4 o0, o1;
        o0.x = accA.x * di + b0.x;
        o0.y = accA.y * di + b0.y;
        o0.z = accA.z * di + b0.z;
        o0.w = accA.w * di + b0.w;
        o1.x = accB.x * di + b1.x;
        o1.y = accB.y * di + b1.y;
        o1.z = accB.z * di + b1.z;
        o1.w = accB.w * di + b1.w;
        float4* orow = (float4*)(out + (size_t)d * DD);
        orow[ql * 2]     = o0;
        orow[ql * 2 + 1] = o1;
    }
}

extern "C" void kernel_launch(void* const* d_in, const int* in_sizes, int n_in,
                              void* d_out, int out_size, void* d_ws, size_t ws_size,
                              hipStream_t stream) {
    const float* x  = (const float*)d_in[0];
    const int*   ei = (const int*)d_in[1];
    const float* W  = (const float*)d_in[2];
    const float* b  = (const float*)d_in[3];
    float* out = (float*)d_out;

    const int n = in_sizes[0] / DD;      // 100000
    const int E = in_sizes[1] / 2;       // 1600000
    const int* src = ei;
    const int* dst = ei + E;

    const int nbuck = (n + 511) >> 9;    // 196

    unsigned short* hs = (unsigned short*)d_ws;              // n*128 bf16 (25.6 MB)
    unsigned short* Wt = hs + (size_t)n * DD;                // 16384 bf16
    int*   binned = (int*)(Wt + DD * DD);                    // nbuck*CAP ints (9.6 MB)
    int*   off    = binned + (size_t)nbuck * CAP;            // n ints
    int*   cnt    = off + n;                                 // n ints
    float* dinv   = (float*)(cnt + n);                       // n floats
    int*   cur    = (int*)(dinv + n);                        // nbuck ints

    const int nblkA = 1024;
    const int chunk = (E + nblkA - 1) / nblkA;               // 1563

    k_init<<<(nbuck + 255) / 256, 256, 0, stream>>>(cur, nbuck);
    k_binA<<<nblkA, 256, 0, stream>>>(src, dst, E, chunk, nbuck, cur, binned);
    k_binB<<<nbuck, 512, 0, stream>>>(binned, cur, off, cnt, dinv, n);
    k_wt  <<<DD * DD / 256, 256, 0, stream>>>(W, Wt);
    k_gemm<<<(n + 255) / 256, 256, 0, stream>>>(x, Wt, dinv, hs, n);
    k_agg <<<(n + 3) / 4, 256, 0, stream>>>((const uint4*)hs, binned, off, cnt,
                                            dinv, b, out, n);
}